// Round 1
// baseline (137.973 us; speedup 1.0000x reference)
//
#include <hip/hip_runtime.h>

#define NN 16
#define NO 32
#define XCOLS 133  // 1 + 4 + 4*NN + 2*NO

__global__ __launch_bounds__(256) void barrier_net_kernel(
    const float* __restrict__ x, const float* __restrict__ noise,
    const float* __restrict__ pnW1, const float* __restrict__ pnb1,
    const float* __restrict__ pnW2, const float* __restrict__ pnb2,
    const float* __restrict__ rnW1, const float* __restrict__ rnb1,
    const float* __restrict__ rnW2, const float* __restrict__ rnb2,
    const float* __restrict__ poW1, const float* __restrict__ pob1,
    const float* __restrict__ poW2, const float* __restrict__ pob2,
    const float* __restrict__ roW1, const float* __restrict__ rob1,
    const float* __restrict__ roW2, const float* __restrict__ rob2,
    const float* __restrict__ psW1, const float* __restrict__ psb1,
    const float* __restrict__ psW2, const float* __restrict__ psb2,
    const float* __restrict__ psW3, const float* __restrict__ psb3,
    float* __restrict__ out)
{
    const int i = blockIdx.x * blockDim.x + threadIdx.x;
    const float* __restrict__ xr = x + (size_t)i * XCOLS;

    const float g0 = xr[1];
    const float g1 = xr[2];

    float bar0 = 0.f, bar1 = 0.f;

    // ---------------- neighbor branch: sum_j relu(v_j @ pnW1 + pnb1) ----------------
    float sn[64];
    #pragma unroll
    for (int f = 0; f < 64; ++f) sn[f] = 0.f;

    for (int j = 0; j < NN; ++j) {
        const float v0 = xr[5 + 4*j + 0];
        const float v1 = xr[5 + 4*j + 1];
        const float v2 = xr[5 + 4*j + 2];
        const float v3 = xr[5 + 4*j + 3];
        // barrier term: P = -pos, D = 0.3
        {
            const float nrm = sqrtf(v0*v0 + v1*v1);
            const float H = nrm - 0.3f;
            const float c = 0.01f / (nrm * H);
            bar0 -= c * v0;
            bar1 -= c * v1;
        }
        #pragma unroll
        for (int f = 0; f < 64; ++f) {
            float t = pnb1[f];
            t = fmaf(v0, pnW1[0*64 + f], t);
            t = fmaf(v1, pnW1[1*64 + f], t);
            t = fmaf(v2, pnW1[2*64 + f], t);
            t = fmaf(v3, pnW1[3*64 + f], t);
            sn[f] += fmaxf(t, 0.f);
        }
    }

    // phi_n pooled second layer: pn = sn @ pnW2 + NN*pnb2   (16)
    float pn[16];
    #pragma unroll
    for (int q = 0; q < 16; ++q) pn[q] = (float)NN * pnb2[q];
    #pragma unroll
    for (int f = 0; f < 64; ++f) {
        #pragma unroll
        for (int q = 0; q < 16; ++q)
            pn[q] = fmaf(sn[f], pnW2[f*16 + q], pn[q]);
    }

    // rho_n: relu(pn @ rnW1 + rnb1) @ rnW2 + rnb2  -> 8 (fused streaming over hidden f)
    float rn[8];
    #pragma unroll
    for (int r = 0; r < 8; ++r) rn[r] = rnb2[r];
    for (int f = 0; f < 64; ++f) {
        float t = rnb1[f];
        #pragma unroll
        for (int q = 0; q < 16; ++q) t = fmaf(pn[q], rnW1[q*64 + f], t);
        t = fmaxf(t, 0.f);
        #pragma unroll
        for (int r = 0; r < 8; ++r) rn[r] = fmaf(t, rnW2[f*8 + r], rn[r]);
    }

    // ---------------- obstacle branch ----------------
    float so[64];
    #pragma unroll
    for (int f = 0; f < 64; ++f) so[f] = 0.f;

    for (int j = 0; j < NO; ++j) {
        const float v0 = xr[5 + 4*NN + 2*j + 0];
        const float v1 = xr[5 + 4*NN + 2*j + 1];
        // barrier term: P = -pos, D = 0.5
        {
            const float nrm = sqrtf(v0*v0 + v1*v1);
            const float H = nrm - 0.5f;
            const float c = 0.01f / (nrm * H);
            bar0 -= c * v0;
            bar1 -= c * v1;
        }
        #pragma unroll
        for (int f = 0; f < 64; ++f) {
            float t = pob1[f];
            t = fmaf(v0, poW1[0*64 + f], t);
            t = fmaf(v1, poW1[1*64 + f], t);
            so[f] += fmaxf(t, 0.f);
        }
    }

    // phi_o pooled second layer: po = so @ poW2 + NO*pob2   (16)
    float po[16];
    #pragma unroll
    for (int q = 0; q < 16; ++q) po[q] = (float)NO * pob2[q];
    #pragma unroll
    for (int f = 0; f < 64; ++f) {
        #pragma unroll
        for (int q = 0; q < 16; ++q)
            po[q] = fmaf(so[f], poW2[f*16 + q], po[q]);
    }

    // rho_o
    float ro[8];
    #pragma unroll
    for (int r = 0; r < 8; ++r) ro[r] = rob2[r];
    for (int f = 0; f < 64; ++f) {
        float t = rob1[f];
        #pragma unroll
        for (int q = 0; q < 16; ++q) t = fmaf(po[q], roW1[q*64 + f], t);
        t = fmaxf(t, 0.f);
        #pragma unroll
        for (int r = 0; r < 8; ++r) ro[r] = fmaf(t, roW2[f*8 + r], ro[r]);
    }

    // ---------------- psi head ----------------
    float h18[18];
    #pragma unroll
    for (int r = 0; r < 8; ++r) { h18[r] = rn[r]; h18[8 + r] = ro[r]; }
    h18[16] = g0;
    h18[17] = g1;

    float ha[64];
    #pragma unroll
    for (int f = 0; f < 64; ++f) {
        float t = psb1[f];
        #pragma unroll
        for (int d = 0; d < 18; ++d) t = fmaf(h18[d], psW1[d*64 + f], t);
        ha[f] = fmaxf(t, 0.f);
    }

    // L2 + L3 fused: stream hidden f2, accumulate the 2 outputs
    float o0 = psb3[0], o1 = psb3[1];
    for (int f2 = 0; f2 < 64; ++f2) {
        float t = psb2[f2];
        #pragma unroll
        for (int f1 = 0; f1 < 64; ++f1) t = fmaf(ha[f1], psW2[f1*64 + f2], t);
        t = fmaxf(t, 0.f);
        o0 = fmaf(t, psW3[f2*2 + 0], o0);
        o1 = fmaf(t, psW3[f2*2 + 1], o1);
    }

    // empty = (tanh+1)/2*4-2 = 2*tanh ; a = tanh(empty+bar+noise) ; out = 2*a
    const float e0 = 2.f * tanhf(o0);
    const float e1 = 2.f * tanhf(o1);
    const float a0 = tanhf(e0 + bar0 + noise[2*i + 0]);
    const float a1 = tanhf(e1 + bar1 + noise[2*i + 1]);
    out[2*i + 0] = 2.f * a0;
    out[2*i + 1] = 2.f * a1;
}

extern "C" void kernel_launch(void* const* d_in, const int* in_sizes, int n_in,
                              void* d_out, int out_size, void* d_ws, size_t ws_size,
                              hipStream_t stream) {
    const float* x    = (const float*)d_in[0];
    const float* nz   = (const float*)d_in[1];
    const float* pnW1 = (const float*)d_in[2];
    const float* pnb1 = (const float*)d_in[3];
    const float* pnW2 = (const float*)d_in[4];
    const float* pnb2 = (const float*)d_in[5];
    const float* rnW1 = (const float*)d_in[6];
    const float* rnb1 = (const float*)d_in[7];
    const float* rnW2 = (const float*)d_in[8];
    const float* rnb2 = (const float*)d_in[9];
    const float* poW1 = (const float*)d_in[10];
    const float* pob1 = (const float*)d_in[11];
    const float* poW2 = (const float*)d_in[12];
    const float* pob2 = (const float*)d_in[13];
    const float* roW1 = (const float*)d_in[14];
    const float* rob1 = (const float*)d_in[15];
    const float* roW2 = (const float*)d_in[16];
    const float* rob2 = (const float*)d_in[17];
    const float* psW1 = (const float*)d_in[18];
    const float* psb1 = (const float*)d_in[19];
    const float* psW2 = (const float*)d_in[20];
    const float* psb2 = (const float*)d_in[21];
    const float* psW3 = (const float*)d_in[22];
    const float* psb3 = (const float*)d_in[23];

    const int b = in_sizes[0] / XCOLS;
    dim3 grid(b / 256), block(256);
    hipLaunchKernelGGL(barrier_net_kernel, grid, block, 0, stream,
        x, nz, pnW1, pnb1, pnW2, pnb2, rnW1, rnb1, rnW2, rnb2,
        poW1, pob1, poW2, pob2, roW1, rob1, roW2, rob2,
        psW1, psb1, psW2, psb2, psW3, psb3, (float*)d_out);
}

// Round 2
// 57.515 us; speedup vs baseline: 2.3989x; 2.3989x over previous
//
#include <hip/hip_runtime.h>

#define NN 16
#define NO 32
#define XCOLS 133

// Block: 256 threads = 4 waves, handling 64 batch elements (lane l <-> element).
// Wave w owns feature slice [16w, 16w+16) of every 64-wide hidden layer, so all
// weight accesses are wave-uniform (scalar loads). Cross-slice pooling via LDS.

__global__ __launch_bounds__(256, 4) void barrier_net_kernel(
    const float* __restrict__ x, const float* __restrict__ noise,
    const float* __restrict__ pnW1, const float* __restrict__ pnb1,
    const float* __restrict__ pnW2, const float* __restrict__ pnb2,
    const float* __restrict__ rnW1, const float* __restrict__ rnb1,
    const float* __restrict__ rnW2, const float* __restrict__ rnb2,
    const float* __restrict__ poW1, const float* __restrict__ pob1,
    const float* __restrict__ poW2, const float* __restrict__ pob2,
    const float* __restrict__ roW1, const float* __restrict__ rob1,
    const float* __restrict__ roW2, const float* __restrict__ rob2,
    const float* __restrict__ psW1, const float* __restrict__ psb1,
    const float* __restrict__ psW2, const float* __restrict__ psb2,
    const float* __restrict__ psW3, const float* __restrict__ psb3,
    float* __restrict__ out)
{
    // LDS: exactly 40960 B -> 4 blocks/CU
    __shared__ float  xs[64 * 64];       // staged point data, swizzled: idx = c*64 + (e ^ (c&31))
    __shared__ float4 bufA[16][64];      // 16 KB: pn/po partials, then ha chunks
    __shared__ float4 bufB[8][64];       // 8 KB: rn/ro partials, then {o0,o1,bar0,bar1} partials

    const int tid = threadIdx.x;
    const int l   = tid & 63;
    const int w   = __builtin_amdgcn_readfirstlane(tid >> 6);  // wave id, scalar
    const int fb  = w * 16;                                    // feature slice base
    const int e0  = blockIdx.x * 64;
    const int e   = e0 + l;

    const float* __restrict__ xrow = x + (size_t)e * XCOLS;
    const float* __restrict__ src  = x + (size_t)e0 * XCOLS;

    const float g0 = xrow[1];
    const float g1 = xrow[2];

    // ---- stage neighbor block: columns [5,69), coalesced global -> swizzled LDS
    #pragma unroll
    for (int it = 0; it < 16; ++it) {
        const int idx = it * 256 + tid;          // 0..4095
        const int ee  = idx >> 6;
        const int c   = idx & 63;
        xs[c * 64 + (ee ^ (c & 31))] = src[(size_t)ee * XCOLS + 5 + c];
    }
    __syncthreads();  // B1

    float bar0 = 0.f, bar1 = 0.f;

    // ================= Phase 1: neighbor L1 slice + pn partial =================
    float sn[16];
    #pragma unroll
    for (int f = 0; f < 16; ++f) sn[f] = 0.f;

    for (int j = 0; j < NN; ++j) {
        const int cb = 4 * j;
        const float v0 = xs[(cb + 0) * 64 + (l ^ ((cb + 0) & 31))];
        const float v1 = xs[(cb + 1) * 64 + (l ^ ((cb + 1) & 31))];
        const float v2 = xs[(cb + 2) * 64 + (l ^ ((cb + 2) & 31))];
        const float v3 = xs[(cb + 3) * 64 + (l ^ ((cb + 3) & 31))];
        #pragma unroll
        for (int f = 0; f < 16; ++f) {
            float t = pnb1[fb + f];
            t = fmaf(v0, pnW1[0 * 64 + fb + f], t);
            t = fmaf(v1, pnW1[1 * 64 + fb + f], t);
            t = fmaf(v2, pnW1[2 * 64 + fb + f], t);
            t = fmaf(v3, pnW1[3 * 64 + fb + f], t);
            sn[f] += fmaxf(t, 0.f);
        }
    }
    // neighbor barrier partials: this wave handles j in [4w, 4w+4)
    #pragma unroll
    for (int jj = 0; jj < 4; ++jj) {
        const int c = 4 * (4 * w + jj);
        const float v0 = xs[(c + 0) * 64 + (l ^ ((c + 0) & 31))];
        const float v1 = xs[(c + 1) * 64 + (l ^ ((c + 1) & 31))];
        const float nrm = sqrtf(v0 * v0 + v1 * v1);
        const float cc  = 0.01f * __builtin_amdgcn_rcpf(nrm * (nrm - 0.3f));
        bar0 -= cc * v0;
        bar1 -= cc * v1;
    }
    // pn partial over this wave's 16 features
    float pn[16];
    #pragma unroll
    for (int q = 0; q < 16; ++q) pn[q] = 0.f;
    for (int f = 0; f < 16; ++f) {
        #pragma unroll
        for (int q = 0; q < 16; ++q)
            pn[q] = fmaf(sn[f], pnW2[(fb + f) * 16 + q], pn[q]);
    }
    #pragma unroll
    for (int qc = 0; qc < 4; ++qc)
        bufA[w * 4 + qc][l] = make_float4(pn[qc*4+0], pn[qc*4+1], pn[qc*4+2], pn[qc*4+3]);
    __syncthreads();  // B2

    // ================= Phase 2: rn partial; stage obstacle block ===============
    #pragma unroll
    for (int q = 0; q < 16; ++q) pn[q] = 16.f * pnb2[q];
    #pragma unroll
    for (int w2 = 0; w2 < 4; ++w2) {
        #pragma unroll
        for (int qc = 0; qc < 4; ++qc) {
            const float4 v = bufA[w2 * 4 + qc][l];
            pn[qc*4+0] += v.x; pn[qc*4+1] += v.y; pn[qc*4+2] += v.z; pn[qc*4+3] += v.w;
        }
    }
    float rp[8];
    #pragma unroll
    for (int r = 0; r < 8; ++r) rp[r] = 0.f;
    for (int f = 0; f < 16; ++f) {
        float t = rnb1[fb + f];
        #pragma unroll
        for (int q = 0; q < 16; ++q) t = fmaf(pn[q], rnW1[q * 64 + fb + f], t);
        t = fmaxf(t, 0.f);
        #pragma unroll
        for (int r = 0; r < 8; ++r) rp[r] = fmaf(t, rnW2[(fb + f) * 8 + r], rp[r]);
    }
    bufB[w * 2 + 0][l] = make_float4(rp[0], rp[1], rp[2], rp[3]);
    bufB[w * 2 + 1][l] = make_float4(rp[4], rp[5], rp[6], rp[7]);
    // stage obstacle block: columns [69,133)
    #pragma unroll
    for (int it = 0; it < 16; ++it) {
        const int idx = it * 256 + tid;
        const int ee  = idx >> 6;
        const int c   = idx & 63;
        xs[c * 64 + (ee ^ (c & 31))] = src[(size_t)ee * XCOLS + 69 + c];
    }
    __syncthreads();  // B3

    // ================= Phase 3: rn full; obstacle L1 slice + po partial ========
    float rn[8];
    #pragma unroll
    for (int rc = 0; rc < 2; ++rc) {
        const float4 a = bufB[0 * 2 + rc][l];
        const float4 b = bufB[1 * 2 + rc][l];
        const float4 c4 = bufB[2 * 2 + rc][l];
        const float4 d = bufB[3 * 2 + rc][l];
        rn[rc*4+0] = a.x + b.x + c4.x + d.x + rnb2[rc*4+0];
        rn[rc*4+1] = a.y + b.y + c4.y + d.y + rnb2[rc*4+1];
        rn[rc*4+2] = a.z + b.z + c4.z + d.z + rnb2[rc*4+2];
        rn[rc*4+3] = a.w + b.w + c4.w + d.w + rnb2[rc*4+3];
    }
    float so[16];
    #pragma unroll
    for (int f = 0; f < 16; ++f) so[f] = 0.f;
    for (int j = 0; j < NO; ++j) {
        const int c = 2 * j;
        const float v0 = xs[(c + 0) * 64 + (l ^ ((c + 0) & 31))];
        const float v1 = xs[(c + 1) * 64 + (l ^ ((c + 1) & 31))];
        #pragma unroll
        for (int f = 0; f < 16; ++f) {
            float t = pob1[fb + f];
            t = fmaf(v0, poW1[0 * 64 + fb + f], t);
            t = fmaf(v1, poW1[1 * 64 + fb + f], t);
            so[f] += fmaxf(t, 0.f);
        }
    }
    // obstacle barrier partials: this wave handles j in [8w, 8w+8)
    #pragma unroll
    for (int jj = 0; jj < 8; ++jj) {
        const int c = 2 * (8 * w + jj);
        const float v0 = xs[(c + 0) * 64 + (l ^ ((c + 0) & 31))];
        const float v1 = xs[(c + 1) * 64 + (l ^ ((c + 1) & 31))];
        const float nrm = sqrtf(v0 * v0 + v1 * v1);
        const float cc  = 0.01f * __builtin_amdgcn_rcpf(nrm * (nrm - 0.5f));
        bar0 -= cc * v0;
        bar1 -= cc * v1;
    }
    float po[16];
    #pragma unroll
    for (int q = 0; q < 16; ++q) po[q] = 0.f;
    for (int f = 0; f < 16; ++f) {
        #pragma unroll
        for (int q = 0; q < 16; ++q)
            po[q] = fmaf(so[f], poW2[(fb + f) * 16 + q], po[q]);
    }
    #pragma unroll
    for (int qc = 0; qc < 4; ++qc)
        bufA[w * 4 + qc][l] = make_float4(po[qc*4+0], po[qc*4+1], po[qc*4+2], po[qc*4+3]);
    __syncthreads();  // B4

    // ================= Phase 4: ro partial =====================================
    #pragma unroll
    for (int q = 0; q < 16; ++q) po[q] = 32.f * pob2[q];
    #pragma unroll
    for (int w2 = 0; w2 < 4; ++w2) {
        #pragma unroll
        for (int qc = 0; qc < 4; ++qc) {
            const float4 v = bufA[w2 * 4 + qc][l];
            po[qc*4+0] += v.x; po[qc*4+1] += v.y; po[qc*4+2] += v.z; po[qc*4+3] += v.w;
        }
    }
    float op[8];
    #pragma unroll
    for (int r = 0; r < 8; ++r) op[r] = 0.f;
    for (int f = 0; f < 16; ++f) {
        float t = rob1[fb + f];
        #pragma unroll
        for (int q = 0; q < 16; ++q) t = fmaf(po[q], roW1[q * 64 + fb + f], t);
        t = fmaxf(t, 0.f);
        #pragma unroll
        for (int r = 0; r < 8; ++r) op[r] = fmaf(t, roW2[(fb + f) * 8 + r], op[r]);
    }
    bufB[w * 2 + 0][l] = make_float4(op[0], op[1], op[2], op[3]);
    bufB[w * 2 + 1][l] = make_float4(op[4], op[5], op[6], op[7]);
    __syncthreads();  // B5

    // ================= Phase 5: ro full; psi L1 slice ==========================
    float ro[8];
    #pragma unroll
    for (int rc = 0; rc < 2; ++rc) {
        const float4 a = bufB[0 * 2 + rc][l];
        const float4 b = bufB[1 * 2 + rc][l];
        const float4 c4 = bufB[2 * 2 + rc][l];
        const float4 d = bufB[3 * 2 + rc][l];
        ro[rc*4+0] = a.x + b.x + c4.x + d.x + rob2[rc*4+0];
        ro[rc*4+1] = a.y + b.y + c4.y + d.y + rob2[rc*4+1];
        ro[rc*4+2] = a.z + b.z + c4.z + d.z + rob2[rc*4+2];
        ro[rc*4+3] = a.w + b.w + c4.w + d.w + rob2[rc*4+3];
    }
    float ha[16];
    for (int f = 0; f < 16; ++f) {
        float t = psb1[fb + f];
        #pragma unroll
        for (int d = 0; d < 8; ++d) t = fmaf(rn[d], psW1[d * 64 + fb + f], t);
        #pragma unroll
        for (int d = 0; d < 8; ++d) t = fmaf(ro[d], psW1[(8 + d) * 64 + fb + f], t);
        t = fmaf(g0, psW1[16 * 64 + fb + f], t);
        t = fmaf(g1, psW1[17 * 64 + fb + f], t);
        ha[f] = fmaxf(t, 0.f);
    }
    #pragma unroll
    for (int c = 0; c < 4; ++c)
        bufA[w * 4 + c][l] = make_float4(ha[c*4+0], ha[c*4+1], ha[c*4+2], ha[c*4+3]);
    __syncthreads();  // B6

    // ================= Phase 6: psi L2 slice + L3 partials =====================
    float t2[16];
    #pragma unroll
    for (int f2 = 0; f2 < 16; ++f2) t2[f2] = psb2[fb + f2];
    for (int c = 0; c < 16; ++c) {
        const float4 hv = bufA[c][l];
        const int f1 = 4 * c;
        #pragma unroll
        for (int f2 = 0; f2 < 16; ++f2) {
            float t = t2[f2];
            t = fmaf(hv.x, psW2[(f1 + 0) * 64 + fb + f2], t);
            t = fmaf(hv.y, psW2[(f1 + 1) * 64 + fb + f2], t);
            t = fmaf(hv.z, psW2[(f1 + 2) * 64 + fb + f2], t);
            t = fmaf(hv.w, psW2[(f1 + 3) * 64 + fb + f2], t);
            t2[f2] = t;
        }
    }
    float o0p = 0.f, o1p = 0.f;
    #pragma unroll
    for (int f2 = 0; f2 < 16; ++f2) {
        const float t = fmaxf(t2[f2], 0.f);
        o0p = fmaf(t, psW3[(fb + f2) * 2 + 0], o0p);
        o1p = fmaf(t, psW3[(fb + f2) * 2 + 1], o1p);
    }
    bufB[w][l] = make_float4(o0p, o1p, bar0, bar1);
    __syncthreads();  // B7

    // ================= Phase 7: finale (wave 0) ================================
    if (w == 0) {
        const float4 a = bufB[0][l];
        const float4 b = bufB[1][l];
        const float4 c4 = bufB[2][l];
        const float4 d = bufB[3][l];
        const float o0 = a.x + b.x + c4.x + d.x + psb3[0];
        const float o1 = a.y + b.y + c4.y + d.y + psb3[1];
        const float b0 = a.z + b.z + c4.z + d.z;
        const float b1 = a.w + b.w + c4.w + d.w;
        const float e0v = 2.f * tanhf(o0);
        const float e1v = 2.f * tanhf(o1);
        const float a0 = tanhf(e0v + b0 + noise[2 * (size_t)e + 0]);
        const float a1 = tanhf(e1v + b1 + noise[2 * (size_t)e + 1]);
        *reinterpret_cast<float2*>(out + 2 * (size_t)e) = make_float2(2.f * a0, 2.f * a1);
    }
}

extern "C" void kernel_launch(void* const* d_in, const int* in_sizes, int n_in,
                              void* d_out, int out_size, void* d_ws, size_t ws_size,
                              hipStream_t stream) {
    const float* x    = (const float*)d_in[0];
    const float* nz   = (const float*)d_in[1];
    const float* pnW1 = (const float*)d_in[2];
    const float* pnb1 = (const float*)d_in[3];
    const float* pnW2 = (const float*)d_in[4];
    const float* pnb2 = (const float*)d_in[5];
    const float* rnW1 = (const float*)d_in[6];
    const float* rnb1 = (const float*)d_in[7];
    const float* rnW2 = (const float*)d_in[8];
    const float* rnb2 = (const float*)d_in[9];
    const float* poW1 = (const float*)d_in[10];
    const float* pob1 = (const float*)d_in[11];
    const float* poW2 = (const float*)d_in[12];
    const float* pob2 = (const float*)d_in[13];
    const float* roW1 = (const float*)d_in[14];
    const float* rob1 = (const float*)d_in[15];
    const float* roW2 = (const float*)d_in[16];
    const float* rob2 = (const float*)d_in[17];
    const float* psW1 = (const float*)d_in[18];
    const float* psb1 = (const float*)d_in[19];
    const float* psW2 = (const float*)d_in[20];
    const float* psb2 = (const float*)d_in[21];
    const float* psW3 = (const float*)d_in[22];
    const float* psb3 = (const float*)d_in[23];

    const int b = in_sizes[0] / XCOLS;
    dim3 grid(b / 64), block(256);
    hipLaunchKernelGGL(barrier_net_kernel, grid, block, 0, stream,
        x, nz, pnW1, pnb1, pnW2, pnb2, rnW1, rnb1, rnW2, rnb2,
        poW1, pob1, poW2, pob2, roW1, rob1, roW2, rob2,
        psW1, psb1, psW2, psb2, psW3, psb3, (float*)d_out);
}